// Round 1
// baseline (6603.831 us; speedup 1.0000x reference)
//
#include <hip/hip_runtime.h>

using u32 = unsigned int;
using u16 = unsigned short;

// ---------------- problem constants ----------------
constexpr int T_ = 100, B_ = 2048, IN_ = 64, H_ = 128, LAT_ = 32;
constexpr size_t X_HAT_SZ = (size_t)B_ * T_ * IN_;   // 13,107,200 floats

// ---------------- ws layout (bytes) ----------------
// b0 (backward dir of enc layer0) stored bf16: [T][B][128]
constexpr size_t WS_B0   = 0;
constexpr size_t O_E0WIH = (size_t)T_ * B_ * H_ * 2;            // 52,428,800
constexpr size_t O_E0WHH = O_E0WIH + (size_t)2 * 64 * 256 * 4;
constexpr size_t O_E1WIH = O_E0WHH + (size_t)2 * 128 * 256 * 4;
constexpr size_t O_E1WHH = O_E1WIH + (size_t)2 * 256 * 256 * 4;
constexpr size_t O_D0WIH = O_E1WHH + (size_t)2 * 128 * 256 * 4;
constexpr size_t O_D0WHH = O_D0WIH + (size_t)64 * 256 * 4;
constexpr size_t O_D1WIH = O_D0WHH + (size_t)128 * 256 * 4;
constexpr size_t O_D1WHH = O_D1WIH + (size_t)128 * 256 * 4;
constexpr size_t O_BE0   = O_D1WHH + (size_t)128 * 256 * 4;     // float2[2][256]
constexpr size_t O_BE1   = O_BE0 + 2 * 256 * 8;
constexpr size_t O_BD0   = O_BE1 + 2 * 256 * 8;
constexpr size_t O_BD1   = O_BD0 + 256 * 8;
constexpr size_t O_FCZT  = O_BD1 + 256 * 8;                      // float[256][32]
constexpr size_t O_FCIT  = O_FCZT + 256 * 32 * 4;                // float[32][256]
constexpr size_t O_FCOT  = O_FCIT + 32 * 256 * 4;                // float[128][64]
constexpr size_t O_FINIT = O_FCOT + 128 * 64 * 4;                // float[B][256]
constexpr size_t WS_NEED = O_FINIT + (size_t)B_ * 256 * 4;       // ~56.3 MB

// ---------------- small helpers ----------------
__device__ __forceinline__ u16 f2bfu(float f) {
  u32 u = __float_as_uint(f);
  u += 0x7fffu + ((u >> 16) & 1u);      // round-to-nearest-even
  return (u16)(u >> 16);
}
__device__ __forceinline__ float bf2f(u32 s) { return __uint_as_float(s << 16); }

__device__ __forceinline__ float sig_f(float v) {
  return __fdividef(1.f, 1.f + __expf(-v));
}
__device__ __forceinline__ float tanh_f(float v) {
  return __fdividef(2.f, 1.f + __expf(-2.f * v)) - 1.f;
}

// ---------------- weight pack kernel ----------------
// Packs each (512,K) fp32 weight into u32[K][256]: element (k,j) = {bf16 W[j][k] | bf16 W[j+256][k] << 16}
// Thread tid of the main kernels then owns gates (tid, tid+256):
//   tid<128  -> i-gate(tid),  g-gate(tid)     (lo, hi)
//   tid>=128 -> f-gate(tid-128), o-gate(tid-128)
__global__ void pack_kernel(const float* e0wih, const float* e0whh, const float* e0b,
                            const float* e1wih, const float* e1whh, const float* e1b,
                            const float* d0wih, const float* d0whh, const float* d0b,
                            const float* d1wih, const float* d1whh, const float* d1b,
                            const float* fczw, const float* fciw, const float* fcow,
                            char* ws) {
  int idx = blockIdx.x * 256 + threadIdx.x;

  const float* srcs[12] = { e0wih, e0wih + 512 * 64, e0whh, e0whh + 512 * 128,
                            e1wih, e1wih + 512 * 256, e1whh, e1whh + 512 * 128,
                            d0wih, d0whh, d1wih, d1whh };
  const int   Ks[12]   = { 64, 64, 128, 128, 256, 256, 128, 128, 64, 128, 128, 128 };
  const size_t offs[12] = { O_E0WIH, O_E0WIH + (size_t)64 * 256 * 4,
                            O_E0WHH, O_E0WHH + (size_t)128 * 256 * 4,
                            O_E1WIH, O_E1WIH + (size_t)256 * 256 * 4,
                            O_E1WHH, O_E1WHH + (size_t)128 * 256 * 4,
                            O_D0WIH, O_D0WHH, O_D1WIH, O_D1WHH };
#pragma unroll
  for (int p = 0; p < 12; ++p) {
    int n = Ks[p] * 256;
    if (idx < n) {
      int k = idx >> 8, j = idx & 255;
      const float* s = srcs[p];
      int K = Ks[p];
      u32 lo = f2bfu(s[(size_t)j * K + k]);
      u32 hi = f2bfu(s[(size_t)(j + 256) * K + k]);
      ((u32*)(ws + offs[p]))[idx] = (hi << 16) | lo;
      return;
    }
    idx -= n;
  }
  // biases -> float2 pairs (gate, gate+256)
  {
    const float* bs[6] = { e0b, e0b + 512, e1b, e1b + 512, d0b, d1b };
    const size_t od[6] = { O_BE0, O_BE0 + 256 * 8, O_BE1, O_BE1 + 256 * 8, O_BD0, O_BD1 };
    if (idx < 6 * 256) {
      int s = idx >> 8, j = idx & 255;
#pragma unroll
      for (int q = 0; q < 6; ++q)
        if (q == s) ((float2*)(ws + od[q]))[j] = make_float2(bs[q][j], bs[q][j + 256]);
      return;
    }
    idx -= 6 * 256;
  }
  if (idx < 8192) {  // fczT [256][32] from fc_z_W (32,256)
    int k = idx >> 5, l = idx & 31;
    ((float*)(ws + O_FCZT))[idx] = fczw[(size_t)l * 256 + k];
    return;
  }
  idx -= 8192;
  if (idx < 8192) {  // fciT [32][256] from fc_init_W (256,32)
    int l = idx >> 8, u = idx & 255;
    ((float*)(ws + O_FCIT))[idx] = fciw[(size_t)u * 32 + l];
    return;
  }
  idx -= 8192;
  if (idx < 8192) {  // fcoT [128][64] from fc_out_W (64,128)
    int k = idx >> 6, o = idx & 63;
    ((float*)(ws + O_FCOT))[idx] = fcow[(size_t)o * 128 + k];
    return;
  }
}
constexpr int PACK_ELEMS = (2*64 + 2*128 + 2*256 + 2*128 + 64 + 128 + 128 + 128) * 256
                           + 6 * 256 + 3 * 8192;   // 435,712
constexpr int PACK_GRID = (PACK_ELEMS + 255) / 256;

// ---------------- gate accumulation ----------------
struct Acc8 { float lo[8]; float hi[8]; };

__device__ __forceinline__ Acc8 acc_init(const float2* __restrict__ bias, int tid) {
  Acc8 a;
  float2 b = bias[tid];
#pragma unroll
  for (int r = 0; r < 8; ++r) { a.lo[r] = b.x; a.hi[r] = b.y; }
  return a;
}

// acc += in[r][0..K) * W^T, weights packed [K][256] u32 (bf16 pair per thread)
__device__ __forceinline__ void seg_acc(const u32* __restrict__ wp, int K,
                                        const float* __restrict__ inb, int stride,
                                        Acc8& a, int tid) {
  u32 w0 = wp[tid], w1 = wp[256 + tid], w2 = wp[512 + tid], w3 = wp[768 + tid];
  for (int k = 0; k < K; k += 4) {
    bool pre = (k + 4) < K;
    const u32* np = wp + (pre ? (size_t)(k + 4) * 256 : 0) + tid;   // prefetch next quad
    u32 n0 = np[0], n1 = np[256], n2 = np[512], n3 = np[768];
    float wl0 = bf2f(w0 & 0xffffu), wh0 = __uint_as_float(w0 & 0xffff0000u);
    float wl1 = bf2f(w1 & 0xffffu), wh1 = __uint_as_float(w1 & 0xffff0000u);
    float wl2 = bf2f(w2 & 0xffffu), wh2 = __uint_as_float(w2 & 0xffff0000u);
    float wl3 = bf2f(w3 & 0xffffu), wh3 = __uint_as_float(w3 & 0xffff0000u);
#pragma unroll
    for (int r = 0; r < 8; ++r) {
      float4 xv = *(const float4*)(inb + r * stride + k);   // LDS broadcast
      a.lo[r] = fmaf(xv.x, wl0, a.lo[r]); a.hi[r] = fmaf(xv.x, wh0, a.hi[r]);
      a.lo[r] = fmaf(xv.y, wl1, a.lo[r]); a.hi[r] = fmaf(xv.y, wh1, a.hi[r]);
      a.lo[r] = fmaf(xv.z, wl2, a.lo[r]); a.hi[r] = fmaf(xv.z, wh2, a.hi[r]);
      a.lo[r] = fmaf(xv.w, wl3, a.lo[r]); a.hi[r] = fmaf(xv.w, wh3, a.hi[r]);
    }
    w0 = n0; w1 = n1; w2 = n2; w3 = n3;
  }
}

// LSTM gate nonlinearity + state update.
// tid<128 publishes i*g via exch; tid>=128 owns c and writes new h (+extra).
template <class F>
__device__ __forceinline__ void cell_finish(const Acc8& a, float* c, float (*hb)[128],
                                            float (*exch)[128], int tid, F&& extra) {
  if (tid < 128) {
#pragma unroll
    for (int r = 0; r < 8; ++r)
      exch[r][tid] = sig_f(a.lo[r]) * tanh_f(a.hi[r]);
  }
  __syncthreads();
  if (tid >= 128) {
    int j = tid - 128;
#pragma unroll
    for (int r = 0; r < 8; ++r) {
      c[r] = sig_f(a.lo[r]) * c[r] + exch[r][j];
      float hv = sig_f(a.hi[r]) * tanh_f(c[r]);
      hb[r][j] = hv;
      extra(r, j, hv);
    }
  }
  __syncthreads();
}

// ---------------- encoder kernel ----------------
// Phase A: enc layer0 backward over t=99..0, store b0 (bf16) to ws.
// Phase B: enc layer0 forward fused with layer1 forward (t=0..99).
// Then: layer1 backward = ONE step from zero state on h0cat[99];
//       fc_z + LayerNorm -> z (written to d_out) ; fc_init -> Finit (ws).
__launch_bounds__(256)
__global__ void enc_kernel(const float* __restrict__ x,
                           const float* __restrict__ fc_z_b, const float* __restrict__ ln_g,
                           const float* __restrict__ ln_b, const float* __restrict__ fc_init_b,
                           char* __restrict__ ws, float* __restrict__ out) {
  __shared__ __align__(16) float xbuf[8][64];
  __shared__ __align__(16) float bbuf[8][128];
  __shared__ __align__(16) float hA[8][128];
  __shared__ __align__(16) float hB[8][128];
  __shared__ __align__(16) float exch[8][128];
  __shared__ __align__(16) float lastout[8][256];
  __shared__ float zbuf[8][32];

  const int tid = threadIdx.x;
  const int row0 = blockIdx.x * 8;
  u16* b0ws = (u16*)(ws + WS_B0);

  // ===== Phase A: backward dir of layer 0 =====
  {
    const u32* Wih = (const u32*)(ws + O_E0WIH) + 64 * 256;    // dir 1
    const u32* Whh = (const u32*)(ws + O_E0WHH) + 128 * 256;
    const float2* Bb = (const float2*)(ws + O_BE0) + 256;
    for (int i = tid; i < 8 * 128; i += 256) (&hA[0][0])[i] = 0.f;
    float cb[8];
#pragma unroll
    for (int r = 0; r < 8; ++r) cb[r] = 0.f;
    __syncthreads();
    for (int s = 0; s < T_; ++s) {
      int t = T_ - 1 - s;
      if (tid < 128) {
        int r = tid >> 4, v = tid & 15;
        *(float4*)&xbuf[r][v * 4] =
            *(const float4*)&x[((size_t)(row0 + r) * T_ + t) * 64 + v * 4];
      }
      __syncthreads();
      Acc8 a = acc_init(Bb, tid);
      seg_acc(Wih, 64, &xbuf[0][0], 64, a, tid);
      seg_acc(Whh, 128, &hA[0][0], 128, a, tid);
      cell_finish(a, cb, hA, exch, tid, [&](int r, int j, float hv) {
        b0ws[((size_t)t * B_ + row0 + r) * 128 + j] = f2bfu(hv);
      });
    }
  }

  // ===== Phase B: fwd layer0 + fwd layer1 =====
  const u32* W0i = (const u32*)(ws + O_E0WIH);
  const u32* W0h = (const u32*)(ws + O_E0WHH);
  const u32* W1i = (const u32*)(ws + O_E1WIH);          // dir0, [256][256]
  const u32* W1h = (const u32*)(ws + O_E1WHH);
  const float2* Be0 = (const float2*)(ws + O_BE0);
  const float2* Be1 = (const float2*)(ws + O_BE1);
  {
    for (int i = tid; i < 8 * 128; i += 256) { (&hA[0][0])[i] = 0.f; (&hB[0][0])[i] = 0.f; }
    float cf0[8], cf1[8];
#pragma unroll
    for (int r = 0; r < 8; ++r) { cf0[r] = 0.f; cf1[r] = 0.f; }
    __syncthreads();
    for (int t = 0; t < T_; ++t) {
      if (tid < 128) {
        int r = tid >> 4, v = tid & 15;
        *(float4*)&xbuf[r][v * 4] =
            *(const float4*)&x[((size_t)(row0 + r) * T_ + t) * 64 + v * 4];
      } else {
        int i = tid - 128;
        uint4 v = *(const uint4*)(b0ws + ((size_t)t * B_ + row0) * 128 + i * 8);
        float* bb = &bbuf[0][0];
        bb[i * 8 + 0] = bf2f(v.x & 0xffffu); bb[i * 8 + 1] = bf2f(v.x >> 16);
        bb[i * 8 + 2] = bf2f(v.y & 0xffffu); bb[i * 8 + 3] = bf2f(v.y >> 16);
        bb[i * 8 + 4] = bf2f(v.z & 0xffffu); bb[i * 8 + 5] = bf2f(v.z >> 16);
        bb[i * 8 + 6] = bf2f(v.w & 0xffffu); bb[i * 8 + 7] = bf2f(v.w >> 16);
      }
      __syncthreads();
      // f0
      Acc8 a = acc_init(Be0, tid);
      seg_acc(W0i, 64, &xbuf[0][0], 64, a, tid);
      seg_acc(W0h, 128, &hA[0][0], 128, a, tid);
      cell_finish(a, cf0, hA, exch, tid, [](int, int, float) {});
      // f1 : h0cat = [f0(new hA) ; b0(bbuf)]
      Acc8 a2 = acc_init(Be1, tid);
      seg_acc(W1i, 128, &hA[0][0], 128, a2, tid);
      seg_acc(W1i + 128 * 256, 128, &bbuf[0][0], 128, a2, tid);
      seg_acc(W1h, 128, &hB[0][0], 128, a2, tid);
      cell_finish(a2, cf1, hB, exch, tid, [](int, int, float) {});
    }
  }

  // ===== layer1 backward: ONE step from zero state on h0cat[99] =====
  {
    const u32* W1ib = W1i + (size_t)256 * 256;       // dir 1
    const float2* Be1b = Be1 + 256;
    Acc8 a = acc_init(Be1b, tid);
    seg_acc(W1ib, 128, &hA[0][0], 128, a, tid);              // f0[99]
    seg_acc(W1ib + 128 * 256, 128, &bbuf[0][0], 128, a, tid); // b0[99]
    if (tid < 128) {
#pragma unroll
      for (int r = 0; r < 8; ++r) {
        exch[r][tid] = sig_f(a.lo[r]) * tanh_f(a.hi[r]);
        lastout[r][tid] = hB[r][tid];                        // f1 final h
      }
    }
    __syncthreads();
    if (tid >= 128) {
      int j = tid - 128;
#pragma unroll
      for (int r = 0; r < 8; ++r) {
        float cv = exch[r][j];                               // c_prev = 0
        lastout[r][128 + j] = sig_f(a.hi[r]) * tanh_f(cv);   // b1 output at t=99
      }
    }
    __syncthreads();
  }

  // ===== fc_z + LayerNorm -> z =====
  {
    int r = tid >> 5, l = tid & 31;
    const float* fczT = (const float*)(ws + O_FCZT);
    float acc = fc_z_b[l];
    for (int k = 0; k < 256; ++k) acc = fmaf(lastout[r][k], fczT[k * 32 + l], acc);
    float s1 = acc, s2 = acc * acc;
#pragma unroll
    for (int off = 16; off >= 1; off >>= 1) {
      s1 += __shfl_xor(s1, off, 32);
      s2 += __shfl_xor(s2, off, 32);
    }
    float mu = s1 * (1.f / 32.f);
    float var = s2 * (1.f / 32.f) - mu * mu;
    float zv = (acc - mu) * rsqrtf(var + 1e-5f) * ln_g[l] + ln_b[l];
    zbuf[r][l] = zv;
    out[X_HAT_SZ + (size_t)(row0 + r) * 32 + l] = zv;
  }
  __syncthreads();

  // ===== fc_init -> Finit (ws), consumed (permuted) by decoder =====
  {
    const float* fciT = (const float*)(ws + O_FCIT);
    float* finit = (float*)(ws + O_FINIT);
    float b = fc_init_b[tid];
#pragma unroll
    for (int r = 0; r < 8; ++r) {
      float acc = b;
#pragma unroll
      for (int l = 0; l < 32; ++l) acc = fmaf(zbuf[r][l], fciT[l * 256 + tid], acc);
      finit[(size_t)(row0 + r) * 256 + tid] = acc;
    }
  }
}

// ---------------- decoder kernel ----------------
// h_init replicates torch's raw .view(L,B,H) reshape of the (B,2H) fc_init output:
//   h0[b][j] = Finit[b>>1][(b&1)*128 + j] ; h1[b][j] = Finit[1024 + (b>>1)][(b&1)*128 + j]
__launch_bounds__(256)
__global__ void dec_kernel(const float* __restrict__ fc_out_b,
                           char* __restrict__ ws, float* __restrict__ out) {
  __shared__ __align__(16) float inbuf[8][64];
  __shared__ __align__(16) float hA[8][128];
  __shared__ __align__(16) float hB[8][128];
  __shared__ __align__(16) float exch[8][128];

  const int tid = threadIdx.x;
  const int row0 = blockIdx.x * 8;
  const float* finit = (const float*)(ws + O_FINIT);

  if (tid < 128) {
#pragma unroll
    for (int r = 0; r < 8; ++r) {
      int b = row0 + r;
      hA[r][tid] = finit[(size_t)(b >> 1) * 256 + (b & 1) * 128 + tid];
    }
  } else {
    int j = tid - 128;
#pragma unroll
    for (int r = 0; r < 8; ++r) {
      int b = row0 + r;
      hB[r][j] = finit[(size_t)(1024 + (b >> 1)) * 256 + (b & 1) * 128 + j];
    }
  }
  for (int i = tid; i < 8 * 64; i += 256) (&inbuf[0][0])[i] = 0.f;
  float c0[8], c1[8];
#pragma unroll
  for (int r = 0; r < 8; ++r) { c0[r] = 0.f; c1[r] = 0.f; }

  const u32* W0i = (const u32*)(ws + O_D0WIH);
  const u32* W0h = (const u32*)(ws + O_D0WHH);
  const u32* W1i = (const u32*)(ws + O_D1WIH);
  const u32* W1h = (const u32*)(ws + O_D1WHH);
  const float2* Bd0 = (const float2*)(ws + O_BD0);
  const float2* Bd1 = (const float2*)(ws + O_BD1);
  const float* fcoT = (const float*)(ws + O_FCOT);
  float ob = fc_out_b[tid & 63];
  __syncthreads();

  for (int t = 0; t < T_; ++t) {
    Acc8 a = acc_init(Bd0, tid);
    seg_acc(W0i, 64, &inbuf[0][0], 64, a, tid);
    seg_acc(W0h, 128, &hA[0][0], 128, a, tid);
    cell_finish(a, c0, hA, exch, tid, [](int, int, float) {});
    Acc8 a2 = acc_init(Bd1, tid);
    seg_acc(W1i, 128, &hA[0][0], 128, a2, tid);
    seg_acc(W1h, 128, &hB[0][0], 128, a2, tid);
    cell_finish(a2, c1, hB, exch, tid, [](int, int, float) {});
    // fc_out + feedback
    {
      int o = tid & 63, rb = tid >> 6;   // rows rb and rb+4
      float p0 = ob, p1 = ob;
      for (int k = 0; k < 128; ++k) {
        float w = fcoT[k * 64 + o];
        p0 = fmaf(hB[rb][k], w, p0);
        p1 = fmaf(hB[rb + 4][k], w, p1);
      }
      out[((size_t)(row0 + rb) * T_ + t) * 64 + o] = p0;
      out[((size_t)(row0 + rb + 4) * T_ + t) * 64 + o] = p1;
      inbuf[rb][o] = p0;
      inbuf[rb + 4][o] = p1;
    }
    __syncthreads();
  }
}

// ---------------- launch ----------------
extern "C" void kernel_launch(void* const* d_in, const int* in_sizes, int n_in,
                              void* d_out, int out_size, void* d_ws, size_t ws_size,
                              hipStream_t stream) {
  const float* x     = (const float*)d_in[0];
  const float* e0wih = (const float*)d_in[1];
  const float* e0whh = (const float*)d_in[2];
  const float* e0b   = (const float*)d_in[3];
  const float* e1wih = (const float*)d_in[4];
  const float* e1whh = (const float*)d_in[5];
  const float* e1b   = (const float*)d_in[6];
  const float* fczw  = (const float*)d_in[7];
  const float* fczb  = (const float*)d_in[8];
  const float* lng   = (const float*)d_in[9];
  const float* lnb   = (const float*)d_in[10];
  const float* fciw  = (const float*)d_in[11];
  const float* fcib  = (const float*)d_in[12];
  const float* d0wih = (const float*)d_in[13];
  const float* d0whh = (const float*)d_in[14];
  const float* d0b   = (const float*)d_in[15];
  const float* d1wih = (const float*)d_in[16];
  const float* d1whh = (const float*)d_in[17];
  const float* d1b   = (const float*)d_in[18];
  const float* fcow  = (const float*)d_in[19];
  const float* fcob  = (const float*)d_in[20];
  char* ws = (char*)d_ws;
  float* out = (float*)d_out;

  pack_kernel<<<PACK_GRID, 256, 0, stream>>>(e0wih, e0whh, e0b, e1wih, e1whh, e1b,
                                             d0wih, d0whh, d0b, d1wih, d1whh, d1b,
                                             fczw, fciw, fcow, ws);
  enc_kernel<<<B_ / 8, 256, 0, stream>>>(x, fczb, lng, lnb, fcib, ws, out);
  dec_kernel<<<B_ / 8, 256, 0, stream>>>(fcob, ws, out);
}

// Round 2
// 1414.735 us; speedup vs baseline: 4.6679x; 4.6679x over previous
//
#include <hip/hip_runtime.h>

using u32 = unsigned int;
using u16 = unsigned short;

typedef __attribute__((ext_vector_type(8))) short bfrag;   // 8 bf16 = 4 VGPR
typedef __attribute__((ext_vector_type(4))) float f32x4;   // MFMA acc

// ---------------- problem constants ----------------
constexpr int T_ = 100, B_ = 2048;
constexpr size_t X_HAT_SZ = (size_t)B_ * T_ * 64;   // 13,107,200 floats

// ---------------- ws layout ----------------
// Packed B-fragment weight arrays (u16 indices). Layout per array:
//   idx = ((kt*NF + nf)*64 + lane)*8 + j  ->  W[nf*16 + (lane&15)][kt*32 + (lane>>4)*8 + j]
constexpr size_t PK_A0  = 0;       // e0 fwd Wih  KT=2
constexpr size_t PK_A1  = 32768;   // e0 bwd Wih  KT=2
constexpr size_t PK_A2  = 65536;   // e0 fwd Whh  KT=4
constexpr size_t PK_A3  = 131072;  // e0 bwd Whh  KT=4
constexpr size_t PK_A4  = 196608;  // e1 fwd Wih  KT=8
constexpr size_t PK_A5  = 327680;  // e1 bwd Wih  KT=8
constexpr size_t PK_A6  = 458752;  // e1 fwd Whh  KT=4
constexpr size_t PK_A7  = 524288;  // d0 Wih      KT=2
constexpr size_t PK_A8  = 557056;  // d0 Whh      KT=4
constexpr size_t PK_A9  = 622592;  // d1 Wih      KT=4
constexpr size_t PK_A10 = 688128;  // d1 Whh      KT=4
constexpr size_t PK_A11 = 753664;  // fc_out      KT=4 NF=4
constexpr size_t PK_END = 761856;  // u16 count
constexpr size_t O_FCZT  = PK_END * 2;          // fp32 [256][32]
constexpr size_t O_FCIT  = O_FCZT + 32768;      // fp32 [32][256]
constexpr size_t O_FINIT = O_FCIT + 32768;      // fp32 [2048][256]
// end ~3.69 MB

// ---------------- helpers ----------------
__device__ __forceinline__ u16 f2bfu(float f) {
  u32 u = __float_as_uint(f);
  u += 0x7fffu + ((u >> 16) & 1u);
  return (u16)(u >> 16);
}
__device__ __forceinline__ float bf2f(u32 s) { return __uint_as_float(s << 16); }

__device__ __forceinline__ float sigf(float v) {
  return __builtin_amdgcn_rcpf(1.f + __expf(-v));
}
__device__ __forceinline__ float tanhfast(float v) {
  float a = fabsf(v);
  float e = __expf(-2.f * a);
  float t = fmaf(-2.f * e, __builtin_amdgcn_rcpf(1.f + e), 1.f);
  return v < 0.f ? -t : t;
}

// A-fragment from padded bf16 LDS tile [16][strideHalf] (strideHalf*2 must be odd*16B)
__device__ __forceinline__ bfrag ldA(const u16* buf, int strideHalf, int kt, int lane) {
  return *(const bfrag*)(buf + (lane & 15) * strideHalf + kt * 32 + (lane >> 4) * 8);
}

// acc[g] += A . W_g  over NKT k-tiles; B-frags streamed from packed global array
template <int NKT>
__device__ __forceinline__ void mm(f32x4 acc[4], const bfrag* A, const u16* WP, int w, int lane) {
#pragma unroll
  for (int kt = 0; kt < NKT; ++kt) {
#pragma unroll
    for (int g = 0; g < 4; ++g) {
      bfrag bw = *(const bfrag*)(WP + (((size_t)(kt * 32 + g * 8 + w)) * 64 + lane) * 8);
      acc[g] = __builtin_amdgcn_mfma_f32_16x16x32_bf16(A[kt], bw, acc[g], 0, 0, 0);
    }
  }
}

// LSTM nonlinearity: lane owns (4 rows, 1 unit); acc = {i,f,g,o}
__device__ __forceinline__ void cellfin(const f32x4 acc[4], float c[4], u16 hq[4]) {
#pragma unroll
  for (int q = 0; q < 4; ++q) {
    float iv = sigf(acc[0][q]);
    float fv = sigf(acc[1][q]);
    float gv = tanhfast(acc[2][q]);
    float ov = sigf(acc[3][q]);
    c[q] = fmaf(fv, c[q], iv * gv);
    hq[q] = f2bfu(ov * tanhfast(c[q]));
  }
}

// ---------------- pack kernel ----------------
__global__ void pack_kernel(const float* e0wih, const float* e0whh,
                            const float* e1wih, const float* e1whh,
                            const float* d0wih, const float* d0whh,
                            const float* d1wih, const float* d1whh,
                            const float* fczw, const float* fciw, const float* fcow,
                            char* ws) {
  int idx = blockIdx.x * 256 + threadIdx.x;
  u16* wsu = (u16*)ws;

  const float* srcs[12] = { e0wih, e0wih + 512 * 64, e0whh, e0whh + 512 * 128,
                            e1wih, e1wih + 512 * 256, e1whh,
                            d0wih, d0whh, d1wih, d1whh, fcow };
  const int Ks[12]  = { 64, 64, 128, 128, 256, 256, 128, 64, 128, 128, 128, 128 };
  const int NFs[12] = { 32, 32, 32, 32, 32, 32, 32, 32, 32, 32, 32, 4 };
  const int cnt[12] = { 32768, 32768, 65536, 65536, 131072, 131072, 65536,
                        32768, 65536, 65536, 65536, 8192 };
  const size_t dst[12] = { PK_A0, PK_A1, PK_A2, PK_A3, PK_A4, PK_A5, PK_A6,
                           PK_A7, PK_A8, PK_A9, PK_A10, PK_A11 };
#pragma unroll
  for (int p = 0; p < 12; ++p) {
    if (idx < cnt[p]) {
      int NF = NFs[p], K = Ks[p];
      int kt = idx / (NF * 512);
      int rem = idx - kt * NF * 512;
      int nf = rem >> 9;
      int li = rem & 511;
      int lane = li >> 3, j = li & 7;
      int n = nf * 16 + (lane & 15);
      int k = kt * 32 + (lane >> 4) * 8 + j;
      wsu[dst[p] + idx] = f2bfu(srcs[p][(size_t)n * K + k]);
      return;
    }
    idx -= cnt[p];
  }
  if (idx < 8192) {  // fczT [256][32] <- fc_z_W (32,256)
    int k = idx >> 5, l = idx & 31;
    ((float*)(ws + O_FCZT))[idx] = fczw[(size_t)l * 256 + k];
    return;
  }
  idx -= 8192;
  if (idx < 8192) {  // fciT [32][256] <- fc_init_W (256,32)
    int l = idx >> 8, o = idx & 255;
    ((float*)(ws + O_FCIT))[idx] = fciw[(size_t)o * 32 + l];
    return;
  }
}
constexpr int PACK_TOTAL = (int)PK_END + 16384;   // 778,240
constexpr int PACK_GRID = (PACK_TOTAL + 255) / 256;

// ---------------- encoder ----------------
__global__ __launch_bounds__(512) void enc_kernel(
    const float* __restrict__ x,
    const float* __restrict__ e0b, const float* __restrict__ e1b,
    const float* __restrict__ fczb, const float* __restrict__ lng,
    const float* __restrict__ lnb, const float* __restrict__ fcib,
    char* __restrict__ ws, float* __restrict__ out) {
  __shared__ __align__(16) u16 xb[16 * 72];
  __shared__ __align__(16) u16 hA[16 * 136];
  __shared__ __align__(16) u16 hB[16 * 136];
  __shared__ __align__(16) u16 bb[16 * 136];
  __shared__ __align__(16) float lastout[16 * 256];
  __shared__ __align__(16) float zbuf[16 * 32];

  const int tid = threadIdx.x;
  const int lane = tid & 63, w = tid >> 6;
  const int chunk = blockIdx.x;
  const int b0r = chunk * 16;
  const u16* wsu = (const u16*)ws;
  u16* scr = (u16*)out;                 // b0 scratch overlays x_hat region
  const int uu = 16 * w + (lane & 15);  // this lane's unit
  const int rg = lane >> 4;             // row group (rows rg*4 .. rg*4+3)

  // ===== Phase A: enc layer0 backward, store b0 to scratch =====
  {
    const float* b = e0b + 512;
    float bi = b[uu], bf = b[128 + uu], bg = b[256 + uu], bo = b[384 + uu];
    for (int i = tid; i < 16 * 136; i += 512) hA[i] = 0;
    float c[4] = {0.f, 0.f, 0.f, 0.f};
    __syncthreads();
    for (int s = 0; s < T_; ++s) {
      int t = T_ - 1 - s;
      {  // stage x_t -> xb (bf16)
        int r = tid >> 5, cp = (tid & 31) * 2;
        float2 v = *(const float2*)(x + ((size_t)(b0r + r) * T_ + t) * 64 + cp);
        *(u32*)&xb[r * 72 + cp] = ((u32)f2bfu(v.y) << 16) | f2bfu(v.x);
      }
      __syncthreads();  // B0
      bfrag ax[2], ah[4];
      ax[0] = ldA(xb, 72, 0, lane); ax[1] = ldA(xb, 72, 1, lane);
#pragma unroll
      for (int kt = 0; kt < 4; ++kt) ah[kt] = ldA(hA, 136, kt, lane);
      f32x4 acc[4] = { {bi, bi, bi, bi}, {bf, bf, bf, bf}, {bg, bg, bg, bg}, {bo, bo, bo, bo} };
      mm<2>(acc, ax, wsu + PK_A1, w, lane);
      mm<4>(acc, ah, wsu + PK_A3, w, lane);
      u16 hq[4];
      cellfin(acc, c, hq);
      __syncthreads();  // B1: all A-reads of hA done
#pragma unroll
      for (int q = 0; q < 4; ++q) {
        int row = rg * 4 + q;
        hA[row * 136 + uu] = hq[q];
        scr[(((size_t)chunk * T_ + t) * 16 + row) * 128 + uu] = hq[q];
      }
      __syncthreads();  // B2: writes visible
    }
  }

  // ===== Phase B: L0 fwd fused with L1 fwd =====
  {
    float b0i, b0f, b0g, b0o, b1i, b1f, b1g, b1o;
    b0i = e0b[uu]; b0f = e0b[128 + uu]; b0g = e0b[256 + uu]; b0o = e0b[384 + uu];
    b1i = e1b[uu]; b1f = e1b[128 + uu]; b1g = e1b[256 + uu]; b1o = e1b[384 + uu];
    for (int i = tid; i < 16 * 136; i += 512) { hA[i] = 0; hB[i] = 0; }
    float c0[4] = {0.f, 0.f, 0.f, 0.f}, c1[4] = {0.f, 0.f, 0.f, 0.f};
    __syncthreads();
    for (int t = 0; t < T_; ++t) {
      {  // stage x_t
        int r = tid >> 5, cp = (tid & 31) * 2;
        float2 v = *(const float2*)(x + ((size_t)(b0r + r) * T_ + t) * 64 + cp);
        *(u32*)&xb[r * 72 + cp] = ((u32)f2bfu(v.y) << 16) | f2bfu(v.x);
      }
      {  // stage b0_t from scratch
#pragma unroll
        for (int i = tid; i < 1024; i += 512) {
          int r = i >> 6, cp = i & 63;
          u32 v = *(const u32*)&scr[(((size_t)chunk * T_ + t) * 16 + r) * 128 + cp * 2];
          *(u32*)&bb[r * 136 + cp * 2] = v;
        }
      }
      __syncthreads();  // B0
      // L0 fwd
      bfrag ax[2], ah[4];
      ax[0] = ldA(xb, 72, 0, lane); ax[1] = ldA(xb, 72, 1, lane);
#pragma unroll
      for (int kt = 0; kt < 4; ++kt) ah[kt] = ldA(hA, 136, kt, lane);
      f32x4 acc[4] = { {b0i,b0i,b0i,b0i}, {b0f,b0f,b0f,b0f}, {b0g,b0g,b0g,b0g}, {b0o,b0o,b0o,b0o} };
      mm<2>(acc, ax, wsu + PK_A0, w, lane);
      mm<4>(acc, ah, wsu + PK_A2, w, lane);
      u16 hq[4];
      cellfin(acc, c0, hq);
      __syncthreads();  // B1
#pragma unroll
      for (int q = 0; q < 4; ++q) hA[(rg * 4 + q) * 136 + uu] = hq[q];
      __syncthreads();  // B2
      // L1 fwd: A = [f0(new) ; b0] K=256, plus hB K=128
      bfrag a8[8], ahb[4];
#pragma unroll
      for (int kt = 0; kt < 4; ++kt) {
        a8[kt] = ldA(hA, 136, kt, lane);
        a8[4 + kt] = ldA(bb, 136, kt, lane);
        ahb[kt] = ldA(hB, 136, kt, lane);
      }
      f32x4 acc1[4] = { {b1i,b1i,b1i,b1i}, {b1f,b1f,b1f,b1f}, {b1g,b1g,b1g,b1g}, {b1o,b1o,b1o,b1o} };
      mm<8>(acc1, a8, wsu + PK_A4, w, lane);
      mm<4>(acc1, ahb, wsu + PK_A6, w, lane);
      u16 hq1[4];
      cellfin(acc1, c1, hq1);
      __syncthreads();  // B3
#pragma unroll
      for (int q = 0; q < 4; ++q) hB[(rg * 4 + q) * 136 + uu] = hq1[q];
      // hB visibility for next iter covered by next B0/B1/B2
    }
    __syncthreads();
  }

  // ===== L1 backward: single step from zero state on h0cat[99] =====
  {
    const float* b = e1b + 512;
    float bi = b[uu], bf = b[128 + uu], bg = b[256 + uu], bo = b[384 + uu];
    bfrag a8[8];
#pragma unroll
    for (int kt = 0; kt < 4; ++kt) {
      a8[kt] = ldA(hA, 136, kt, lane);       // f0[99]
      a8[4 + kt] = ldA(bb, 136, kt, lane);   // b0[99]
    }
    f32x4 acc[4] = { {bi, bi, bi, bi}, {bf, bf, bf, bf}, {bg, bg, bg, bg}, {bo, bo, bo, bo} };
    mm<8>(acc, a8, wsu + PK_A5, w, lane);
#pragma unroll
    for (int q = 0; q < 4; ++q) {
      float iv = sigf(acc[0][q]);
      float gv = tanhfast(acc[2][q]);
      float ov = sigf(acc[3][q]);
      float cv = iv * gv;                       // c_prev = 0
      lastout[(rg * 4 + q) * 256 + 128 + uu] = ov * tanhfast(cv);
    }
    // f1 final h
    for (int i = tid; i < 2048; i += 512) {
      int r = i >> 7, cc = i & 127;
      lastout[r * 256 + cc] = bf2f(hB[r * 136 + cc]);
    }
    __syncthreads();
  }

  // ===== fc_z + LayerNorm -> z =====
  {
    int r = tid >> 5, l = tid & 31;
    const float* fczT = (const float*)(ws + O_FCZT);
    float acc = fczb[l];
    for (int k = 0; k < 256; ++k) acc = fmaf(lastout[r * 256 + k], fczT[k * 32 + l], acc);
    float s1 = acc, s2 = acc * acc;
#pragma unroll
    for (int off = 16; off >= 1; off >>= 1) {
      s1 += __shfl_xor(s1, off, 32);
      s2 += __shfl_xor(s2, off, 32);
    }
    float mu = s1 * (1.f / 32.f);
    float var = s2 * (1.f / 32.f) - mu * mu;
    float zv = (acc - mu) * rsqrtf(var + 1e-5f) * lng[l] + lnb[l];
    zbuf[r * 32 + l] = zv;
    out[X_HAT_SZ + (size_t)(b0r + r) * 32 + l] = zv;
  }
  __syncthreads();

  // ===== fc_init -> finit (ws) =====
  {
    const float* fciT = (const float*)(ws + O_FCIT);
    float* finit = (float*)(ws + O_FINIT);
    int o = tid & 255, half = tid >> 8;
#pragma unroll
    for (int rr = 0; rr < 8; ++rr) {
      int r = half * 8 + rr;
      float acc = fcib[o];
#pragma unroll
      for (int l = 0; l < 32; ++l) acc = fmaf(zbuf[r * 32 + l], fciT[l * 256 + o], acc);
      finit[(size_t)(b0r + r) * 256 + o] = acc;
    }
  }
}

// ---------------- decoder ----------------
__global__ __launch_bounds__(512) void dec_kernel(
    const float* __restrict__ d0b, const float* __restrict__ d1b,
    const float* __restrict__ fcob,
    char* __restrict__ ws, float* __restrict__ out) {
  __shared__ __align__(16) u16 xb[16 * 72];
  __shared__ __align__(16) u16 hA[16 * 136];
  __shared__ __align__(16) u16 hB[16 * 136];

  const int tid = threadIdx.x;
  const int lane = tid & 63, w = tid >> 6;
  const int chunk = blockIdx.x;
  const int b0r = chunk * 16;
  const u16* wsu = (const u16*)ws;
  const float* finit = (const float*)(ws + O_FINIT);
  const int uu = 16 * w + (lane & 15);
  const int rg = lane >> 4;

  for (int i = tid; i < 16 * 72; i += 512) xb[i] = 0;
  for (int i = tid; i < 2048; i += 512) {
    int r = i >> 7, j = i & 127;
    int b = b0r + r;
    hA[r * 136 + j] = f2bfu(finit[(size_t)(b >> 1) * 256 + (b & 1) * 128 + j]);
    hB[r * 136 + j] = f2bfu(finit[(size_t)(1024 + (b >> 1)) * 256 + (b & 1) * 128 + j]);
  }
  float d0i = d0b[uu], d0f = d0b[128 + uu], d0g = d0b[256 + uu], d0o = d0b[384 + uu];
  float d1i = d1b[uu], d1f = d1b[128 + uu], d1g = d1b[256 + uu], d1o = d1b[384 + uu];
  float fob = (w < 4) ? fcob[16 * w + (lane & 15)] : 0.f;
  float c0[4] = {0.f, 0.f, 0.f, 0.f}, c1[4] = {0.f, 0.f, 0.f, 0.f};
  __syncthreads();

  for (int t = 0; t < T_; ++t) {
    // L0
    bfrag ax[2], ah[4];
    ax[0] = ldA(xb, 72, 0, lane); ax[1] = ldA(xb, 72, 1, lane);
#pragma unroll
    for (int kt = 0; kt < 4; ++kt) ah[kt] = ldA(hA, 136, kt, lane);
    f32x4 acc[4] = { {d0i,d0i,d0i,d0i}, {d0f,d0f,d0f,d0f}, {d0g,d0g,d0g,d0g}, {d0o,d0o,d0o,d0o} };
    mm<2>(acc, ax, wsu + PK_A7, w, lane);
    mm<4>(acc, ah, wsu + PK_A8, w, lane);
    u16 hq[4];
    cellfin(acc, c0, hq);
    __syncthreads();  // B1
#pragma unroll
    for (int q = 0; q < 4; ++q) hA[(rg * 4 + q) * 136 + uu] = hq[q];
    __syncthreads();  // B2
    // L1
    bfrag a0[4], a1[4];
#pragma unroll
    for (int kt = 0; kt < 4; ++kt) {
      a0[kt] = ldA(hA, 136, kt, lane);
      a1[kt] = ldA(hB, 136, kt, lane);
    }
    f32x4 acc1[4] = { {d1i,d1i,d1i,d1i}, {d1f,d1f,d1f,d1f}, {d1g,d1g,d1g,d1g}, {d1o,d1o,d1o,d1o} };
    mm<4>(acc1, a0, wsu + PK_A9, w, lane);
    mm<4>(acc1, a1, wsu + PK_A10, w, lane);
    u16 hq1[4];
    cellfin(acc1, c1, hq1);
    __syncthreads();  // B3
#pragma unroll
    for (int q = 0; q < 4; ++q) hB[(rg * 4 + q) * 136 + uu] = hq1[q];
    __syncthreads();  // B4: hB visible for fc_out
    // fc_out (waves 0-3) + feedback
    if (w < 4) {
      bfrag ah1[4];
#pragma unroll
      for (int kt = 0; kt < 4; ++kt) ah1[kt] = ldA(hB, 136, kt, lane);
      f32x4 accP = {fob, fob, fob, fob};
#pragma unroll
      for (int kt = 0; kt < 4; ++kt) {
        bfrag bw = *(const bfrag*)(wsu + PK_A11 + (((size_t)(kt * 4 + w)) * 64 + lane) * 8);
        accP = __builtin_amdgcn_mfma_f32_16x16x32_bf16(ah1[kt], bw, accP, 0, 0, 0);
      }
      int oc = 16 * w + (lane & 15);
#pragma unroll
      for (int q = 0; q < 4; ++q) {
        int row = rg * 4 + q;
        float p = accP[q];
        out[((size_t)(b0r + row) * T_ + t) * 64 + oc] = p;
        xb[row * 72 + oc] = f2bfu(p);
      }
    }
    __syncthreads();  // B0 for next iter (xb visible)
  }
}

// ---------------- launch ----------------
extern "C" void kernel_launch(void* const* d_in, const int* in_sizes, int n_in,
                              void* d_out, int out_size, void* d_ws, size_t ws_size,
                              hipStream_t stream) {
  const float* x     = (const float*)d_in[0];
  const float* e0wih = (const float*)d_in[1];
  const float* e0whh = (const float*)d_in[2];
  const float* e0b   = (const float*)d_in[3];
  const float* e1wih = (const float*)d_in[4];
  const float* e1whh = (const float*)d_in[5];
  const float* e1b   = (const float*)d_in[6];
  const float* fczw  = (const float*)d_in[7];
  const float* fczb  = (const float*)d_in[8];
  const float* lng   = (const float*)d_in[9];
  const float* lnb   = (const float*)d_in[10];
  const float* fciw  = (const float*)d_in[11];
  const float* fcib  = (const float*)d_in[12];
  const float* d0wih = (const float*)d_in[13];
  const float* d0whh = (const float*)d_in[14];
  const float* d0b   = (const float*)d_in[15];
  const float* d1wih = (const float*)d_in[16];
  const float* d1whh = (const float*)d_in[17];
  const float* d1b   = (const float*)d_in[18];
  const float* fcow  = (const float*)d_in[19];
  const float* fcob  = (const float*)d_in[20];
  char* ws = (char*)d_ws;
  float* out = (float*)d_out;

  pack_kernel<<<PACK_GRID, 256, 0, stream>>>(e0wih, e0whh, e1wih, e1whh,
                                             d0wih, d0whh, d1wih, d1whh,
                                             fczw, fciw, fcow, ws);
  enc_kernel<<<128, 512, 0, stream>>>(x, e0b, e1b, fczb, lng, lnb, fcib, ws, out);
  dec_kernel<<<128, 512, 0, stream>>>(d0b, d1b, fcob, ws, out);
}

// Round 3
// 1022.872 us; speedup vs baseline: 6.4562x; 1.3831x over previous
//
#include <hip/hip_runtime.h>

using u32 = unsigned int;
using u16 = unsigned short;

typedef __attribute__((ext_vector_type(8))) short bfrag;   // 8 bf16 = 4 VGPR
typedef __attribute__((ext_vector_type(4))) float f32x4;   // MFMA acc

// ---------------- problem constants ----------------
constexpr int T_ = 100, B_ = 2048;
constexpr size_t X_HAT_SZ = (size_t)B_ * T_ * 64;   // 13,107,200 floats

// ---------------- ws layout ----------------
// f0 (enc L0 forward output) bf16 [T][B][128] at byte 0 (52,428,800 B)
// then packed weights (u16 idx base PKB), then small fp32 tables.
constexpr size_t PKB    = 26214400;        // u16 index of packed-weight base
constexpr size_t PK_A0  = PKB + 0;         // e0 fwd Wih  KT=2
constexpr size_t PK_A1  = PKB + 32768;     // e0 bwd Wih  KT=2
constexpr size_t PK_A2  = PKB + 65536;     // e0 fwd Whh  KT=4
constexpr size_t PK_A3  = PKB + 131072;    // e0 bwd Whh  KT=4
constexpr size_t PK_A4  = PKB + 196608;    // e1 fwd Wih  KT=8
constexpr size_t PK_A5  = PKB + 327680;    // e1 bwd Wih  KT=8
constexpr size_t PK_A6  = PKB + 458752;    // e1 fwd Whh  KT=4
constexpr size_t PK_A7  = PKB + 524288;    // d0 Wih      KT=2
constexpr size_t PK_A8  = PKB + 557056;    // d0 Whh      KT=4
constexpr size_t PK_A9  = PKB + 622592;    // d1 Wih      KT=4
constexpr size_t PK_A10 = PKB + 688128;    // d1 Whh      KT=4
constexpr size_t PK_A11 = PKB + 753664;    // fc_out      KT=4 NF=4
constexpr size_t PK_ENDU = PKB + 761856;
constexpr size_t O_FCZT  = PK_ENDU * 2;            // fp32 [256][32]
constexpr size_t O_FCIT  = O_FCZT + 32768;         // fp32 [32][256]
constexpr size_t O_FINIT = O_FCIT + 32768;         // fp32 [2048][256]
// end = O_FINIT + 2 MiB  ~= 56.1 MB

// ---------------- helpers ----------------
__device__ __forceinline__ u16 f2bfu(float f) {
  u32 u = __float_as_uint(f);
  u += 0x7fffu + ((u >> 16) & 1u);
  return (u16)(u >> 16);
}
__device__ __forceinline__ float bf2f(u32 s) { return __uint_as_float(s << 16); }

__device__ __forceinline__ float sigf(float v) {
  return __builtin_amdgcn_rcpf(1.f + __expf(-v));
}
__device__ __forceinline__ float tanhfast(float v) {
  float a = fabsf(v);
  float e = __expf(-2.f * a);
  float t = fmaf(-2.f * e, __builtin_amdgcn_rcpf(1.f + e), 1.f);
  return v < 0.f ? -t : t;
}

// A-fragment from padded bf16 LDS tile
__device__ __forceinline__ bfrag ldA(const u16* buf, int strideHalf, int kt, int lane) {
  return *(const bfrag*)(buf + (lane & 15) * strideHalf + kt * 32 + (lane >> 4) * 8);
}

// streaming mm (B-frags from global) — used only in the one-step enc tail
template <int NKT>
__device__ __forceinline__ void mm(f32x4 acc[4], const bfrag* A, const u16* WP, int w, int lane) {
#pragma unroll
  for (int kt = 0; kt < NKT; ++kt) {
#pragma unroll
    for (int g = 0; g < 4; ++g) {
      bfrag bw = *(const bfrag*)(WP + (((size_t)(kt * 32 + g * 8 + w)) * 64 + lane) * 8);
      acc[g] = __builtin_amdgcn_mfma_f32_16x16x32_bf16(A[kt], bw, acc[g], 0, 0, 0);
    }
  }
}

// persisted-weight load: W[kt*4+g]
template <int NKT>
__device__ __forceinline__ void loadW(bfrag* W, const u16* wsu, size_t base, int w, int lane) {
#pragma unroll
  for (int kt = 0; kt < NKT; ++kt)
#pragma unroll
    for (int g = 0; g < 4; ++g)
      W[kt * 4 + g] = *(const bfrag*)(wsu + base + (((size_t)(kt * 32 + g * 8 + w)) * 64 + lane) * 8);
}

// mm with persisted (register) B-frags, A read from LDS per kt
template <int NKT>
__device__ __forceinline__ void mmR(f32x4 acc[4], const u16* lds, int sh, const bfrag* W, int lane) {
#pragma unroll
  for (int kt = 0; kt < NKT; ++kt) {
    bfrag a = ldA(lds, sh, kt, lane);
#pragma unroll
    for (int g = 0; g < 4; ++g)
      acc[g] = __builtin_amdgcn_mfma_f32_16x16x32_bf16(a, W[kt * 4 + g], acc[g], 0, 0, 0);
  }
}

// LSTM nonlinearity: lane owns (4 rows, 1 unit); acc = {i,f,g,o}
__device__ __forceinline__ void cellfin(const f32x4 acc[4], float c[4], u16 hq[4]) {
#pragma unroll
  for (int q = 0; q < 4; ++q) {
    float iv = sigf(acc[0][q]);
    float fv = sigf(acc[1][q]);
    float gv = tanhfast(acc[2][q]);
    float ov = sigf(acc[3][q]);
    c[q] = fmaf(fv, c[q], iv * gv);
    hq[q] = f2bfu(ov * tanhfast(c[q]));
  }
}

// ---------------- pack kernel ----------------
__global__ void pack_kernel(const float* e0wih, const float* e0whh,
                            const float* e1wih, const float* e1whh,
                            const float* d0wih, const float* d0whh,
                            const float* d1wih, const float* d1whh,
                            const float* fczw, const float* fciw, const float* fcow,
                            char* ws) {
  int idx = blockIdx.x * 256 + threadIdx.x;
  u16* wsu = (u16*)ws;

  const float* srcs[12] = { e0wih, e0wih + 512 * 64, e0whh, e0whh + 512 * 128,
                            e1wih, e1wih + 512 * 256, e1whh,
                            d0wih, d0whh, d1wih, d1whh, fcow };
  const int Ks[12]  = { 64, 64, 128, 128, 256, 256, 128, 64, 128, 128, 128, 128 };
  const int NFs[12] = { 32, 32, 32, 32, 32, 32, 32, 32, 32, 32, 32, 4 };
  const int cnt[12] = { 32768, 32768, 65536, 65536, 131072, 131072, 65536,
                        32768, 65536, 65536, 65536, 8192 };
  const size_t dst[12] = { PK_A0, PK_A1, PK_A2, PK_A3, PK_A4, PK_A5, PK_A6,
                           PK_A7, PK_A8, PK_A9, PK_A10, PK_A11 };
#pragma unroll
  for (int p = 0; p < 12; ++p) {
    if (idx < cnt[p]) {
      int NF = NFs[p], K = Ks[p];
      int kt = idx / (NF * 512);
      int rem = idx - kt * NF * 512;
      int nf = rem >> 9;
      int li = rem & 511;
      int lane = li >> 3, j = li & 7;
      int n = nf * 16 + (lane & 15);
      int k = kt * 32 + (lane >> 4) * 8 + j;
      wsu[dst[p] + idx] = f2bfu(srcs[p][(size_t)n * K + k]);
      return;
    }
    idx -= cnt[p];
  }
  if (idx < 8192) {  // fczT [256][32] <- fc_z_W (32,256)
    int k = idx >> 5, l = idx & 31;
    ((float*)(ws + O_FCZT))[idx] = fczw[(size_t)l * 256 + k];
    return;
  }
  idx -= 8192;
  if (idx < 8192) {  // fciT [32][256] <- fc_init_W (256,32)
    int l = idx >> 8, o = idx & 255;
    ((float*)(ws + O_FCIT))[idx] = fciw[(size_t)o * 32 + l];
    return;
  }
}
constexpr int PACK_TOTAL = 761856 + 16384;
constexpr int PACK_GRID = (PACK_TOTAL + 255) / 256;

// ---------------- encoder ----------------
__global__ __launch_bounds__(512, 2) void enc_kernel(
    const float* __restrict__ x,
    const float* __restrict__ e0b, const float* __restrict__ e1b,
    const float* __restrict__ fczb, const float* __restrict__ lng,
    const float* __restrict__ lnb, const float* __restrict__ fcib,
    char* __restrict__ ws, float* __restrict__ out) {
  __shared__ __align__(16) u16 xb[16 * 72];
  __shared__ __align__(16) u16 cat[16 * 264];   // [f0 | b0] K=256, stride 264
  __shared__ __align__(16) u16 hA[16 * 136];
  __shared__ __align__(16) u16 hB[16 * 136];
  __shared__ __align__(16) float lastout[16 * 256];
  __shared__ __align__(16) float zbuf[16 * 32];

  const int tid = threadIdx.x;
  const int lane = tid & 63, w = tid >> 6;
  const int chunk = blockIdx.x;
  const int b0r = chunk * 16;
  const u16* wsu = (const u16*)ws;
  u16* scr = (u16*)out;          // b0 scratch overlays x_hat region
  u16* f0g = (u16*)ws;           // f0 scratch at ws byte 0
  const int uu = 16 * w + (lane & 15);
  const int rg = lane >> 4;

  const int xr = tid >> 5, xcp = (tid & 31) * 2;   // x staging slot
  auto ldx = [&](int t) {
    return *(const float2*)(x + ((size_t)(b0r + xr) * T_ + t) * 64 + xcp);
  };

  // ===== P1: enc L0 backward (weights fully in registers) =====
  {
    bfrag W1[8], W3[16];
    loadW<2>(W1, wsu, PK_A1, w, lane);
    loadW<4>(W3, wsu, PK_A3, w, lane);
    const float* b = e0b + 512;
    float bi = b[uu], bf = b[128 + uu], bg = b[256 + uu], bo = b[384 + uu];
    for (int i = tid; i < 16 * 136; i += 512) hA[i] = 0;
    float c[4] = {0.f, 0.f, 0.f, 0.f};
    float2 pf = ldx(T_ - 1);
    __syncthreads();
    for (int s = 0; s < T_; ++s) {
      int t = T_ - 1 - s;
      *(u32*)&xb[xr * 72 + xcp] = ((u32)f2bfu(pf.y) << 16) | f2bfu(pf.x);
      __syncthreads();  // B0
      if (s < T_ - 1) pf = ldx(t - 1);
      f32x4 acc[4] = { {bi,bi,bi,bi}, {bf,bf,bf,bf}, {bg,bg,bg,bg}, {bo,bo,bo,bo} };
      mmR<2>(acc, xb, 72, W1, lane);
      mmR<4>(acc, hA, 136, W3, lane);
      u16 hq[4];
      cellfin(acc, c, hq);
      __syncthreads();  // B1
#pragma unroll
      for (int q = 0; q < 4; ++q) {
        int row = rg * 4 + q;
        hA[row * 136 + uu] = hq[q];
        scr[(((size_t)chunk * T_ + t) * 16 + row) * 128 + uu] = hq[q];
      }
      __syncthreads();  // B2
    }
  }

  // ===== P2: enc L0 forward (weights in registers), store f0 =====
  {
    bfrag W0[8], W2[16];
    loadW<2>(W0, wsu, PK_A0, w, lane);
    loadW<4>(W2, wsu, PK_A2, w, lane);
    float bi = e0b[uu], bf = e0b[128 + uu], bg = e0b[256 + uu], bo = e0b[384 + uu];
    for (int i = tid; i < 16 * 136; i += 512) hA[i] = 0;
    float c[4] = {0.f, 0.f, 0.f, 0.f};
    float2 pf = ldx(0);
    __syncthreads();
    for (int t = 0; t < T_; ++t) {
      *(u32*)&xb[xr * 72 + xcp] = ((u32)f2bfu(pf.y) << 16) | f2bfu(pf.x);
      __syncthreads();  // B0
      if (t < T_ - 1) pf = ldx(t + 1);
      f32x4 acc[4] = { {bi,bi,bi,bi}, {bf,bf,bf,bf}, {bg,bg,bg,bg}, {bo,bo,bo,bo} };
      mmR<2>(acc, xb, 72, W0, lane);
      mmR<4>(acc, hA, 136, W2, lane);
      u16 hq[4];
      cellfin(acc, c, hq);
      __syncthreads();  // B1
#pragma unroll
      for (int q = 0; q < 4; ++q) {
        int row = rg * 4 + q;
        hA[row * 136 + uu] = hq[q];
        f0g[(((size_t)chunk * T_ + t) * 16 + row) * 128 + uu] = hq[q];
      }
      __syncthreads();  // B2
    }
  }

  // ===== P3: enc L1 forward (A4+A6 in registers), A = [f0 ; b0] staged =====
  {
    bfrag W4[32], W6[16];
    loadW<8>(W4, wsu, PK_A4, w, lane);
    loadW<4>(W6, wsu, PK_A6, w, lane);
    float bi = e1b[uu], bf = e1b[128 + uu], bg = e1b[256 + uu], bo = e1b[384 + uu];
    for (int i = tid; i < 16 * 136; i += 512) hB[i] = 0;
    float c[4] = {0.f, 0.f, 0.f, 0.f};
    const u32* f0u = (const u32*)f0g;
    const u32* b0u = (const u32*)scr;
    const int prow = tid >> 6, pc4 = tid & 63;
    auto ldrow = [&](const u32* src, int t, int r) {
      return src[(((size_t)chunk * T_ + t) * 16 + r) * 64 + pc4];
    };
    u32 pa = ldrow(f0u, 0, prow), pb = ldrow(f0u, 0, prow + 8);
    u32 pc = ldrow(b0u, 0, prow), pd = ldrow(b0u, 0, prow + 8);
    __syncthreads();
    for (int t = 0; t < T_; ++t) {
      *(u32*)&cat[prow * 264 + pc4 * 2] = pa;
      *(u32*)&cat[(prow + 8) * 264 + pc4 * 2] = pb;
      *(u32*)&cat[prow * 264 + 128 + pc4 * 2] = pc;
      *(u32*)&cat[(prow + 8) * 264 + 128 + pc4 * 2] = pd;
      __syncthreads();  // B0
      if (t < T_ - 1) {
        pa = ldrow(f0u, t + 1, prow); pb = ldrow(f0u, t + 1, prow + 8);
        pc = ldrow(b0u, t + 1, prow); pd = ldrow(b0u, t + 1, prow + 8);
      }
      f32x4 acc[4] = { {bi,bi,bi,bi}, {bf,bf,bf,bf}, {bg,bg,bg,bg}, {bo,bo,bo,bo} };
      mmR<8>(acc, cat, 264, W4, lane);
      mmR<4>(acc, hB, 136, W6, lane);
      u16 hq[4];
      cellfin(acc, c, hq);
      __syncthreads();  // B1
#pragma unroll
      for (int q = 0; q < 4; ++q) hB[(rg * 4 + q) * 136 + uu] = hq[q];
      __syncthreads();  // B2
    }
  }

  // ===== L1 backward: single step from zero state on h0cat[99] (cat holds t=99) =====
  {
    const float* b = e1b + 512;
    float bi = b[uu], bf = b[128 + uu], bg = b[256 + uu], bo = b[384 + uu];
    bfrag a8[8];
#pragma unroll
    for (int kt = 0; kt < 8; ++kt) a8[kt] = ldA(cat, 264, kt, lane);
    f32x4 acc[4] = { {bi,bi,bi,bi}, {bf,bf,bf,bf}, {bg,bg,bg,bg}, {bo,bo,bo,bo} };
    mm<8>(acc, a8, wsu + PK_A5, w, lane);
#pragma unroll
    for (int q = 0; q < 4; ++q) {
      float iv = sigf(acc[0][q]);
      float gv = tanhfast(acc[2][q]);
      float ov = sigf(acc[3][q]);
      float cv = iv * gv;                       // c_prev = 0
      lastout[(rg * 4 + q) * 256 + 128 + uu] = ov * tanhfast(cv);
    }
    for (int i = tid; i < 2048; i += 512) {
      int r = i >> 7, cc = i & 127;
      lastout[r * 256 + cc] = bf2f(hB[r * 136 + cc]);
    }
    __syncthreads();
  }

  // ===== fc_z + LayerNorm -> z =====
  {
    int r = tid >> 5, l = tid & 31;
    const float* fczT = (const float*)(ws + O_FCZT);
    float acc = fczb[l];
    for (int k = 0; k < 256; ++k) acc = fmaf(lastout[r * 256 + k], fczT[k * 32 + l], acc);
    float s1 = acc, s2 = acc * acc;
#pragma unroll
    for (int off = 16; off >= 1; off >>= 1) {
      s1 += __shfl_xor(s1, off, 32);
      s2 += __shfl_xor(s2, off, 32);
    }
    float mu = s1 * (1.f / 32.f);
    float var = s2 * (1.f / 32.f) - mu * mu;
    float zv = (acc - mu) * rsqrtf(var + 1e-5f) * lng[l] + lnb[l];
    zbuf[r * 32 + l] = zv;
    out[X_HAT_SZ + (size_t)(b0r + r) * 32 + l] = zv;
  }
  __syncthreads();

  // ===== fc_init -> finit (ws) =====
  {
    const float* fciT = (const float*)(ws + O_FCIT);
    float* finit = (float*)(ws + O_FINIT);
    int o = tid & 255, half = tid >> 8;
#pragma unroll
    for (int rr = 0; rr < 8; ++rr) {
      int r = half * 8 + rr;
      float acc = fcib[o];
#pragma unroll
      for (int l = 0; l < 32; ++l) acc = fmaf(zbuf[r * 32 + l], fciT[l * 256 + o], acc);
      finit[(size_t)(b0r + r) * 256 + o] = acc;
    }
  }
}

// ---------------- decoder ----------------
// persists A7,A8,A10,A11 in VGPRs; streams A9 through one 8-frag window.
__global__ __launch_bounds__(512, 2) void dec_kernel(
    const float* __restrict__ d0b, const float* __restrict__ d1b,
    const float* __restrict__ fcob,
    char* __restrict__ ws, float* __restrict__ out) {
  __shared__ __align__(16) u16 xb[16 * 72];
  __shared__ __align__(16) u16 hA[16 * 136];
  __shared__ __align__(16) u16 hB[16 * 136];

  const int tid = threadIdx.x;
  const int lane = tid & 63, w = tid >> 6;
  const int chunk = blockIdx.x;
  const int b0r = chunk * 16;
  const u16* wsu = (const u16*)ws;
  const float* finit = (const float*)(ws + O_FINIT);
  const int uu = 16 * w + (lane & 15);
  const int rg = lane >> 4;

  bfrag W7[8], W8[16], W10[16], W11[4];
  loadW<2>(W7, wsu, PK_A7, w, lane);
  loadW<4>(W8, wsu, PK_A8, w, lane);
  loadW<4>(W10, wsu, PK_A10, w, lane);
  {
    int wf = w & 3;
#pragma unroll
    for (int kt = 0; kt < 4; ++kt)
      W11[kt] = *(const bfrag*)(wsu + PK_A11 + (((size_t)(kt * 4 + wf)) * 64 + lane) * 8);
  }
  auto ld9 = [&](bfrag* d, int ktbase) {
#pragma unroll
    for (int kt = 0; kt < 2; ++kt)
#pragma unroll
      for (int g = 0; g < 4; ++g)
        d[kt * 4 + g] = *(const bfrag*)(wsu + PK_A9 +
            (((size_t)((ktbase + kt) * 32 + g * 8 + w)) * 64 + lane) * 8);
  };
  bfrag s9[8];
  ld9(s9, 0);

  for (int i = tid; i < 16 * 72; i += 512) xb[i] = 0;
  for (int i = tid; i < 2048; i += 512) {
    int r = i >> 7, j = i & 127;
    int b = b0r + r;
    hA[r * 136 + j] = f2bfu(finit[(size_t)(b >> 1) * 256 + (b & 1) * 128 + j]);
    hB[r * 136 + j] = f2bfu(finit[(size_t)(1024 + (b >> 1)) * 256 + (b & 1) * 128 + j]);
  }
  float d0i = d0b[uu], d0f = d0b[128 + uu], d0g = d0b[256 + uu], d0o = d0b[384 + uu];
  float d1i = d1b[uu], d1f = d1b[128 + uu], d1g = d1b[256 + uu], d1o = d1b[384 + uu];
  float fob = (w < 4) ? fcob[16 * w + (lane & 15)] : 0.f;
  float c0[4] = {0.f, 0.f, 0.f, 0.f}, c1[4] = {0.f, 0.f, 0.f, 0.f};
  __syncthreads();

  for (int t = 0; t < T_; ++t) {
    // ---- L0 ----
    f32x4 acc[4] = { {d0i,d0i,d0i,d0i}, {d0f,d0f,d0f,d0f}, {d0g,d0g,d0g,d0g}, {d0o,d0o,d0o,d0o} };
    mmR<2>(acc, xb, 72, W7, lane);
    mmR<4>(acc, hA, 136, W8, lane);
    u16 hq[4];
    cellfin(acc, c0, hq);
    __syncthreads();  // B1
#pragma unroll
    for (int q = 0; q < 4; ++q) hA[(rg * 4 + q) * 136 + uu] = hq[q];
    __syncthreads();  // B2
    // ---- L1 ----
    f32x4 acc1[4] = { {d1i,d1i,d1i,d1i}, {d1f,d1f,d1f,d1f}, {d1g,d1g,d1g,d1g}, {d1o,d1o,d1o,d1o} };
#pragma unroll
    for (int kt = 0; kt < 2; ++kt) {
      bfrag a = ldA(hA, 136, kt, lane);
#pragma unroll
      for (int g = 0; g < 4; ++g)
        acc1[g] = __builtin_amdgcn_mfma_f32_16x16x32_bf16(a, s9[kt * 4 + g], acc1[g], 0, 0, 0);
    }
    ld9(s9, 2);                           // reload window kt=2,3 (hidden by A10 block)
    mmR<4>(acc1, hB, 136, W10, lane);
#pragma unroll
    for (int kt = 0; kt < 2; ++kt) {
      bfrag a = ldA(hA, 136, 2 + kt, lane);
#pragma unroll
      for (int g = 0; g < 4; ++g)
        acc1[g] = __builtin_amdgcn_mfma_f32_16x16x32_bf16(a, s9[kt * 4 + g], acc1[g], 0, 0, 0);
    }
    u16 hq1[4];
    cellfin(acc1, c1, hq1);
    ld9(s9, 0);                           // window back to kt=0,1 for next step
    __syncthreads();  // B3
#pragma unroll
    for (int q = 0; q < 4; ++q) hB[(rg * 4 + q) * 136 + uu] = hq1[q];
    __syncthreads();  // B4
    // ---- fc_out + feedback (waves 0-3) ----
    if (w < 4) {
      bfrag ah1[4];
#pragma unroll
      for (int kt = 0; kt < 4; ++kt) ah1[kt] = ldA(hB, 136, kt, lane);
      f32x4 accP = {fob, fob, fob, fob};
#pragma unroll
      for (int kt = 0; kt < 4; ++kt)
        accP = __builtin_amdgcn_mfma_f32_16x16x32_bf16(ah1[kt], W11[kt], accP, 0, 0, 0);
      int oc = 16 * w + (lane & 15);
#pragma unroll
      for (int q = 0; q < 4; ++q) {
        int row = rg * 4 + q;
        float p = accP[q];
        out[((size_t)(b0r + row) * T_ + t) * 64 + oc] = p;
        xb[row * 72 + oc] = f2bfu(p);
      }
    }
    __syncthreads();  // B5: xb/out visible for next step
  }
}

// ---------------- launch ----------------
extern "C" void kernel_launch(void* const* d_in, const int* in_sizes, int n_in,
                              void* d_out, int out_size, void* d_ws, size_t ws_size,
                              hipStream_t stream) {
  const float* x     = (const float*)d_in[0];
  const float* e0wih = (const float*)d_in[1];
  const float* e0whh = (const float*)d_in[2];
  const float* e0b   = (const float*)d_in[3];
  const float* e1wih = (const float*)d_in[4];
  const float* e1whh = (const float*)d_in[5];
  const float* e1b   = (const float*)d_in[6];
  const float* fczw  = (const float*)d_in[7];
  const float* fczb  = (const float*)d_in[8];
  const float* lng   = (const float*)d_in[9];
  const float* lnb   = (const float*)d_in[10];
  const float* fciw  = (const float*)d_in[11];
  const float* fcib  = (const float*)d_in[12];
  const float* d0wih = (const float*)d_in[13];
  const float* d0whh = (const float*)d_in[14];
  const float* d0b   = (const float*)d_in[15];
  const float* d1wih = (const float*)d_in[16];
  const float* d1whh = (const float*)d_in[17];
  const float* d1b   = (const float*)d_in[18];
  const float* fcow  = (const float*)d_in[19];
  const float* fcob  = (const float*)d_in[20];
  char* ws = (char*)d_ws;
  float* out = (float*)d_out;

  pack_kernel<<<PACK_GRID, 256, 0, stream>>>(e0wih, e0whh, e1wih, e1whh,
                                             d0wih, d0whh, d1wih, d1whh,
                                             fczw, fciw, fcow, ws);
  enc_kernel<<<128, 512, 0, stream>>>(x, e0b, e1b, fczb, lng, lnb, fcib, ws, out);
  dec_kernel<<<128, 512, 0, stream>>>(d0b, d1b, fcob, ws, out);
}

// Round 4
// 585.828 us; speedup vs baseline: 11.2727x; 1.7460x over previous
//
#include <hip/hip_runtime.h>

using u32 = unsigned int;
using u16 = unsigned short;

typedef __attribute__((ext_vector_type(8))) short bfrag;   // 8 bf16 = 4 VGPR
typedef __attribute__((ext_vector_type(4))) float f32x4;   // MFMA acc

// ---------------- problem constants ----------------
constexpr int T_ = 100, B_ = 2048;
constexpr size_t X_HAT_SZ = (size_t)B_ * T_ * 64;   // 13,107,200 floats

// ---------------- ws layout ----------------
// f0 (enc L0 forward output) bf16 [T][B/16][16][128] at byte 0 (52,428,800 B)
// then packed weights (u16 idx base PKB), then small fp32 tables.
constexpr size_t PKB    = 26214400;        // u16 index of packed-weight base
constexpr size_t PK_A0  = PKB + 0;         // e0 fwd Wih  KT=2
constexpr size_t PK_A1  = PKB + 32768;     // e0 bwd Wih  KT=2
constexpr size_t PK_A2  = PKB + 65536;     // e0 fwd Whh  KT=4
constexpr size_t PK_A3  = PKB + 131072;    // e0 bwd Whh  KT=4
constexpr size_t PK_A4  = PKB + 196608;    // e1 fwd Wih  KT=8
constexpr size_t PK_A5  = PKB + 327680;    // e1 bwd Wih  KT=8
constexpr size_t PK_A6  = PKB + 458752;    // e1 fwd Whh  KT=4
constexpr size_t PK_A7  = PKB + 524288;    // d0 Wih      KT=2
constexpr size_t PK_A8  = PKB + 557056;    // d0 Whh      KT=4
constexpr size_t PK_A9  = PKB + 622592;    // d1 Wih      KT=4
constexpr size_t PK_A10 = PKB + 688128;    // d1 Whh      KT=4
constexpr size_t PK_A11 = PKB + 753664;    // fc_out      KT=4 NF=4  (contiguous after A10)
constexpr size_t PK_ENDU = PKB + 761856;
constexpr size_t O_FCZT  = PK_ENDU * 2;            // fp32 [256][32]
constexpr size_t O_FCIT  = O_FCZT + 32768;         // fp32 [32][256]
constexpr size_t O_FINIT = O_FCIT + 32768;         // fp32 [2048][256]

// ---------------- helpers ----------------
__device__ __forceinline__ u16 f2bfu(float f) {
  u32 u = __float_as_uint(f);
  u += 0x7fffu + ((u >> 16) & 1u);
  return (u16)(u >> 16);
}
__device__ __forceinline__ float bf2f(u32 s) { return __uint_as_float(s << 16); }

__device__ __forceinline__ float sigf(float v) {
  return __builtin_amdgcn_rcpf(1.f + __expf(-v));
}
__device__ __forceinline__ float tanhfast(float v) {
  float a = fabsf(v);
  float e = __expf(-2.f * a);
  float t = fmaf(-2.f * e, __builtin_amdgcn_rcpf(1.f + e), 1.f);
  return v < 0.f ? -t : t;
}

// A-fragment from padded bf16 LDS tile
__device__ __forceinline__ bfrag ldA(const u16* buf, int strideHalf, int kt, int lane) {
  return *(const bfrag*)(buf + (lane & 15) * strideHalf + kt * 32 + (lane >> 4) * 8);
}

// streaming mm (B-frags from global) — one-shot enc tail only
template <int NKT>
__device__ __forceinline__ void mm(f32x4 acc[4], const bfrag* A, const u16* WP, int w, int lane) {
#pragma unroll
  for (int kt = 0; kt < NKT; ++kt) {
#pragma unroll
    for (int g = 0; g < 4; ++g) {
      bfrag bw = *(const bfrag*)(WP + (((size_t)(kt * 32 + g * 8 + w)) * 64 + lane) * 8);
      acc[g] = __builtin_amdgcn_mfma_f32_16x16x32_bf16(A[kt], bw, acc[g], 0, 0, 0);
    }
  }
}

// persisted-weight load into registers: W[kt*4+g]
template <int NKT>
__device__ __forceinline__ void loadW(bfrag* W, const u16* wsu, size_t base, int w, int lane) {
#pragma unroll
  for (int kt = 0; kt < NKT; ++kt)
#pragma unroll
    for (int g = 0; g < 4; ++g)
      W[kt * 4 + g] = *(const bfrag*)(wsu + base + (((size_t)(kt * 32 + g * 8 + w)) * 64 + lane) * 8);
}

// mm with persisted (register) B-frags
template <int NKT>
__device__ __forceinline__ void mmR(f32x4 acc[4], const u16* lds, int sh, const bfrag* W, int lane) {
#pragma unroll
  for (int kt = 0; kt < NKT; ++kt) {
    bfrag a = ldA(lds, sh, kt, lane);
#pragma unroll
    for (int g = 0; g < 4; ++g)
      acc[g] = __builtin_amdgcn_mfma_f32_16x16x32_bf16(a, W[kt * 4 + g], acc[g], 0, 0, 0);
  }
}

// mm with LDS-resident B-frags (same packed layout, frag_id*1024B + lane*16B)
template <int NKT>
__device__ __forceinline__ void mmL(f32x4 acc[4], const u16* alds, int sh,
                                    const u16* wlds, int w, int lane) {
#pragma unroll
  for (int kt = 0; kt < NKT; ++kt) {
    bfrag a = ldA(alds, sh, kt, lane);
#pragma unroll
    for (int g = 0; g < 4; ++g) {
      bfrag b = *(const bfrag*)(wlds + ((size_t)(kt * 32 + g * 8 + w) * 64 + lane) * 8);
      acc[g] = __builtin_amdgcn_mfma_f32_16x16x32_bf16(a, b, acc[g], 0, 0, 0);
    }
  }
}

// LSTM nonlinearity: lane owns (4 rows, 1 unit); acc = {i,f,g,o}
__device__ __forceinline__ void cellfin(const f32x4 acc[4], float c[4], u16 hq[4]) {
#pragma unroll
  for (int q = 0; q < 4; ++q) {
    float iv = sigf(acc[0][q]);
    float fv = sigf(acc[1][q]);
    float gv = tanhfast(acc[2][q]);
    float ov = sigf(acc[3][q]);
    c[q] = fmaf(fv, c[q], iv * gv);
    hq[q] = f2bfu(ov * tanhfast(c[q]));
  }
}

// ---------------- pack kernel ----------------
__global__ void pack_kernel(const float* e0wih, const float* e0whh,
                            const float* e1wih, const float* e1whh,
                            const float* d0wih, const float* d0whh,
                            const float* d1wih, const float* d1whh,
                            const float* fczw, const float* fciw, const float* fcow,
                            char* ws) {
  int idx = blockIdx.x * 256 + threadIdx.x;
  u16* wsu = (u16*)ws;

  const float* srcs[12] = { e0wih, e0wih + 512 * 64, e0whh, e0whh + 512 * 128,
                            e1wih, e1wih + 512 * 256, e1whh,
                            d0wih, d0whh, d1wih, d1whh, fcow };
  const int Ks[12]  = { 64, 64, 128, 128, 256, 256, 128, 64, 128, 128, 128, 128 };
  const int NFs[12] = { 32, 32, 32, 32, 32, 32, 32, 32, 32, 32, 32, 4 };
  const int cnt[12] = { 32768, 32768, 65536, 65536, 131072, 131072, 65536,
                        32768, 65536, 65536, 65536, 8192 };
  const size_t dst[12] = { PK_A0, PK_A1, PK_A2, PK_A3, PK_A4, PK_A5, PK_A6,
                           PK_A7, PK_A8, PK_A9, PK_A10, PK_A11 };
#pragma unroll
  for (int p = 0; p < 12; ++p) {
    if (idx < cnt[p]) {
      int NF = NFs[p], K = Ks[p];
      int kt = idx / (NF * 512);
      int rem = idx - kt * NF * 512;
      int nf = rem >> 9;
      int li = rem & 511;
      int lane = li >> 3, j = li & 7;
      int n = nf * 16 + (lane & 15);
      int k = kt * 32 + (lane >> 4) * 8 + j;
      wsu[dst[p] + idx] = f2bfu(srcs[p][(size_t)n * K + k]);
      return;
    }
    idx -= cnt[p];
  }
  if (idx < 8192) {  // fczT [256][32] <- fc_z_W (32,256)
    int k = idx >> 5, l = idx & 31;
    ((float*)(ws + O_FCZT))[idx] = fczw[(size_t)l * 256 + k];
    return;
  }
  idx -= 8192;
  if (idx < 8192) {  // fciT [32][256] <- fc_init_W (256,32)
    int l = idx >> 8, o = idx & 255;
    ((float*)(ws + O_FCIT))[idx] = fciw[(size_t)o * 32 + l];
    return;
  }
}
constexpr int PACK_TOTAL = 761856 + 16384;
constexpr int PACK_GRID = (PACK_TOTAL + 255) / 256;

// ---------------- enc L0: bwd (blocks 0-127) and fwd (blocks 128-255), concurrent ----------------
__global__ __launch_bounds__(512, 2) void enc01_kernel(
    const float* __restrict__ x, const float* __restrict__ e0b,
    char* __restrict__ ws, float* __restrict__ out) {
  __shared__ __align__(16) u16 xb[16 * 72];
  __shared__ __align__(16) u16 hA[16 * 136];

  const int tid = threadIdx.x;
  const int lane = tid & 63, w = tid >> 6;
  const int mode = blockIdx.x >> 7;          // 0 = backward, 1 = forward
  const int chunk = blockIdx.x & 127;
  const int b0r = chunk * 16;
  const u16* wsu = (const u16*)ws;
  const int uu = 16 * w + (lane & 15);
  const int rg = lane >> 4;
  const bool rev = (mode == 0);
  u16* dst = rev ? (u16*)out : (u16*)ws;     // b0 -> out-scratch ; f0 -> ws

  bfrag Wi[8], Wh[16];
  loadW<2>(Wi, wsu, rev ? PK_A1 : PK_A0, w, lane);
  loadW<4>(Wh, wsu, rev ? PK_A3 : PK_A2, w, lane);
  const float* bias = e0b + (rev ? 512 : 0);
  const float bi = bias[uu], bf = bias[128 + uu], bg = bias[256 + uu], bo = bias[384 + uu];

  const int xr = tid >> 5, xcp = (tid & 31) * 2;
  auto ldx = [&](int t) {
    return *(const float2*)(x + ((size_t)(b0r + xr) * T_ + t) * 64 + xcp);
  };

  for (int i = tid; i < 16 * 136; i += 512) hA[i] = 0;
  float c[4] = {0.f, 0.f, 0.f, 0.f};
  float2 pf = ldx(rev ? T_ - 1 : 0);
  *(u32*)&xb[xr * 72 + xcp] = ((u32)f2bfu(pf.y) << 16) | f2bfu(pf.x);
  __syncthreads();
  pf = ldx(rev ? T_ - 2 : 1);

  for (int s = 0; s < T_; ++s) {
    int t = rev ? T_ - 1 - s : s;
    f32x4 acc[4] = { {bi,bi,bi,bi}, {bf,bf,bf,bf}, {bg,bg,bg,bg}, {bo,bo,bo,bo} };
    mmR<2>(acc, xb, 72, Wi, lane);
    mmR<4>(acc, hA, 136, Wh, lane);
    u16 hq[4];
    cellfin(acc, c, hq);
    __syncthreads();  // B1: all reads of xb/hA done
#pragma unroll
    for (int q = 0; q < 4; ++q) {
      int row = rg * 4 + q;
      hA[row * 136 + uu] = hq[q];
      dst[(((size_t)chunk * T_ + t) * 16 + row) * 128 + uu] = hq[q];
    }
    if (s < T_ - 1)
      *(u32*)&xb[xr * 72 + xcp] = ((u32)f2bfu(pf.y) << 16) | f2bfu(pf.x);
    if (s < T_ - 2) pf = ldx(rev ? t - 2 : t + 2);
    __syncthreads();  // B2
  }
}

// ---------------- enc L1 fwd + tail (128 WGs) ----------------
// A4 (Wih, 32 frags) persisted in VGPRs; A6 (Whh) resident in LDS.
constexpr int E2_A6   = 0;                 // 131072 B
constexpr int E2_CAT  = 131072;            // 16*264*2 = 8448
constexpr int E2_HB   = 139520;            // 16*136*2 = 4352  -> 143872 total
constexpr int E2_LAST = 0;                 // alias over A6 after the loop (16 KB)
constexpr int E2_ZB   = 16384;             // zbuf (2 KB)

__global__ __launch_bounds__(512, 1) void enc2_kernel(
    const float* __restrict__ e1b, const float* __restrict__ fczb,
    const float* __restrict__ lng, const float* __restrict__ lnb,
    const float* __restrict__ fcib,
    char* __restrict__ ws, float* __restrict__ out) {
  __shared__ __align__(16) char sm[143872];
  u16* A6L = (u16*)(sm + E2_A6);
  u16* cat = (u16*)(sm + E2_CAT);
  u16* hB  = (u16*)(sm + E2_HB);

  const int tid = threadIdx.x;
  const int lane = tid & 63, w = tid >> 6;
  const int chunk = blockIdx.x;
  const int b0r = chunk * 16;
  const u16* wsu = (const u16*)ws;
  const int uu = 16 * w + (lane & 15);
  const int rg = lane >> 4;

  {  // copy A6 -> LDS (131072 B = 8192 uint4)
    const uint4* src = (const uint4*)(wsu + PK_A6);
    uint4* d = (uint4*)A6L;
    for (int i = tid; i < 8192; i += 512) d[i] = src[i];
  }
  bfrag W4[32];
  loadW<8>(W4, wsu, PK_A4, w, lane);
  const float bi = e1b[uu], bf = e1b[128 + uu], bg = e1b[256 + uu], bo = e1b[384 + uu];
  for (int i = tid; i < 16 * 136; i += 512) hB[i] = 0;
  float c[4] = {0.f, 0.f, 0.f, 0.f};

  const u32* f0u = (const u32*)ws;    // f0 from enc01 fwd
  const u32* b0u = (const u32*)out;   // b0 from enc01 bwd
  const int prow = tid >> 6, pc4 = tid & 63;
  auto ldrow = [&](const u32* src, int t, int r) {
    return src[(((size_t)chunk * T_ + t) * 16 + r) * 64 + pc4];
  };
  u32 pa = ldrow(f0u, 0, prow), pb = ldrow(f0u, 0, prow + 8);
  u32 pc = ldrow(b0u, 0, prow), pd = ldrow(b0u, 0, prow + 8);
  *(u32*)&cat[prow * 264 + pc4 * 2] = pa;
  *(u32*)&cat[(prow + 8) * 264 + pc4 * 2] = pb;
  *(u32*)&cat[prow * 264 + 128 + pc4 * 2] = pc;
  *(u32*)&cat[(prow + 8) * 264 + 128 + pc4 * 2] = pd;
  __syncthreads();
  pa = ldrow(f0u, 1, prow); pb = ldrow(f0u, 1, prow + 8);
  pc = ldrow(b0u, 1, prow); pd = ldrow(b0u, 1, prow + 8);

  for (int t = 0; t < T_; ++t) {
    f32x4 acc[4] = { {bi,bi,bi,bi}, {bf,bf,bf,bf}, {bg,bg,bg,bg}, {bo,bo,bo,bo} };
    mmR<8>(acc, cat, 264, W4, lane);
    mmL<4>(acc, hB, 136, A6L, w, lane);
    u16 hq[4];
    cellfin(acc, c, hq);
    __syncthreads();  // B1
#pragma unroll
    for (int q = 0; q < 4; ++q) hB[(rg * 4 + q) * 136 + uu] = hq[q];
    if (t < T_ - 1) {
      *(u32*)&cat[prow * 264 + pc4 * 2] = pa;
      *(u32*)&cat[(prow + 8) * 264 + pc4 * 2] = pb;
      *(u32*)&cat[prow * 264 + 128 + pc4 * 2] = pc;
      *(u32*)&cat[(prow + 8) * 264 + 128 + pc4 * 2] = pd;
    }
    if (t < T_ - 2) {
      pa = ldrow(f0u, t + 2, prow); pb = ldrow(f0u, t + 2, prow + 8);
      pc = ldrow(b0u, t + 2, prow); pd = ldrow(b0u, t + 2, prow + 8);
    }
    __syncthreads();  // B2
  }

  // ===== L1 backward: single step from zero state on h0cat[99] (cat holds t=99) =====
  float* lastout = (float*)(sm + E2_LAST);   // clobbers A6L (done with it)
  float* zbuf = (float*)(sm + E2_ZB);
  {
    const float* b = e1b + 512;
    float bi2 = b[uu], bf2 = b[128 + uu], bg2 = b[256 + uu], bo2 = b[384 + uu];
    bfrag a8[8];
#pragma unroll
    for (int kt = 0; kt < 8; ++kt) a8[kt] = ldA(cat, 264, kt, lane);
    f32x4 acc[4] = { {bi2,bi2,bi2,bi2}, {bf2,bf2,bf2,bf2}, {bg2,bg2,bg2,bg2}, {bo2,bo2,bo2,bo2} };
    mm<8>(acc, a8, wsu + PK_A5, w, lane);
#pragma unroll
    for (int q = 0; q < 4; ++q) {
      float iv = sigf(acc[0][q]);
      float gv = tanhfast(acc[2][q]);
      float ov = sigf(acc[3][q]);
      float cv = iv * gv;                       // c_prev = 0
      lastout[(rg * 4 + q) * 256 + 128 + uu] = ov * tanhfast(cv);
    }
    for (int i = tid; i < 2048; i += 512) {
      int r = i >> 7, cc = i & 127;
      lastout[r * 256 + cc] = bf2f(hB[r * 136 + cc]);
    }
    __syncthreads();
  }

  // ===== fc_z + LayerNorm -> z =====
  {
    int r = tid >> 5, l = tid & 31;
    const float* fczT = (const float*)(ws + O_FCZT);
    float acc = fczb[l];
    for (int k = 0; k < 256; ++k) acc = fmaf(lastout[r * 256 + k], fczT[k * 32 + l], acc);
    float s1 = acc, s2 = acc * acc;
#pragma unroll
    for (int off = 16; off >= 1; off >>= 1) {
      s1 += __shfl_xor(s1, off, 32);
      s2 += __shfl_xor(s2, off, 32);
    }
    float mu = s1 * (1.f / 32.f);
    float var = s2 * (1.f / 32.f) - mu * mu;
    float zv = (acc - mu) * rsqrtf(var + 1e-5f) * lng[l] + lnb[l];
    zbuf[r * 32 + l] = zv;
    out[X_HAT_SZ + (size_t)(b0r + r) * 32 + l] = zv;
  }
  __syncthreads();

  // ===== fc_init -> finit (ws) =====
  {
    const float* fciT = (const float*)(ws + O_FCIT);
    float* finit = (float*)(ws + O_FINIT);
    int o = tid & 255, half = tid >> 8;
#pragma unroll
    for (int rr = 0; rr < 8; ++rr) {
      int r = half * 8 + rr;
      float acc = fcib[o];
#pragma unroll
      for (int l = 0; l < 32; ++l) acc = fmaf(zbuf[r * 32 + l], fciT[l * 256 + o], acc);
      finit[(size_t)(b0r + r) * 256 + o] = acc;
    }
  }
}

// ---------------- decoder ----------------
// A7,A8,A9 persisted in VGPRs (40 frags = 160); A10,A11 resident in LDS (144 KB).
constexpr int DC_A10 = 0;           // 131072
constexpr int DC_A11 = 131072;      // 16384
constexpr int DC_XB  = 147456;      // 16*72*2 = 2304
constexpr int DC_HA  = 149760;      // 4352
constexpr int DC_HB  = 154112;      // 4352 -> 158464 total
__global__ __launch_bounds__(512, 1) void dec_kernel(
    const float* __restrict__ d0b, const float* __restrict__ d1b,
    const float* __restrict__ fcob,
    char* __restrict__ ws, float* __restrict__ out) {
  __shared__ __align__(16) char sm[158464];
  u16* A10L = (u16*)(sm + DC_A10);
  u16* A11L = (u16*)(sm + DC_A11);
  u16* xb   = (u16*)(sm + DC_XB);
  u16* hA   = (u16*)(sm + DC_HA);
  u16* hB   = (u16*)(sm + DC_HB);

  const int tid = threadIdx.x;
  const int lane = tid & 63, w = tid >> 6;
  const int chunk = blockIdx.x;
  const int b0r = chunk * 16;
  const u16* wsu = (const u16*)ws;
  const float* finit = (const float*)(ws + O_FINIT);
  const int uu = 16 * w + (lane & 15);
  const int rg = lane >> 4;

  {  // copy A10+A11 (contiguous, 147456 B = 9216 uint4) -> LDS
    const uint4* src = (const uint4*)(wsu + PK_A10);
    uint4* d = (uint4*)A10L;
    for (int i = tid; i < 9216; i += 512) d[i] = src[i];
  }
  bfrag W7[8], W8[16], W9[16];
  loadW<2>(W7, wsu, PK_A7, w, lane);
  loadW<4>(W8, wsu, PK_A8, w, lane);
  loadW<4>(W9, wsu, PK_A9, w, lane);

  for (int i = tid; i < 16 * 72; i += 512) xb[i] = 0;
  for (int i = tid; i < 2048; i += 512) {
    int r = i >> 7, j = i & 127;
    int b = b0r + r;
    hA[r * 136 + j] = f2bfu(finit[(size_t)(b >> 1) * 256 + (b & 1) * 128 + j]);
    hB[r * 136 + j] = f2bfu(finit[(size_t)(1024 + (b >> 1)) * 256 + (b & 1) * 128 + j]);
  }
  const float d0i = d0b[uu], d0f = d0b[128 + uu], d0g = d0b[256 + uu], d0o = d0b[384 + uu];
  const float d1i = d1b[uu], d1f = d1b[128 + uu], d1g = d1b[256 + uu], d1o = d1b[384 + uu];
  const float fob = (w < 4) ? fcob[16 * w + (lane & 15)] : 0.f;
  float c0[4] = {0.f, 0.f, 0.f, 0.f}, c1[4] = {0.f, 0.f, 0.f, 0.f};
  __syncthreads();

  for (int t = 0; t < T_; ++t) {
    // ---- L0 ----
    f32x4 acc[4] = { {d0i,d0i,d0i,d0i}, {d0f,d0f,d0f,d0f}, {d0g,d0g,d0g,d0g}, {d0o,d0o,d0o,d0o} };
    mmR<2>(acc, xb, 72, W7, lane);
    mmR<4>(acc, hA, 136, W8, lane);
    u16 hq[4];
    cellfin(acc, c0, hq);
    __syncthreads();  // B1
#pragma unroll
    for (int q = 0; q < 4; ++q) hA[(rg * 4 + q) * 136 + uu] = hq[q];
    __syncthreads();  // B2
    // ---- L1 ----
    f32x4 acc1[4] = { {d1i,d1i,d1i,d1i}, {d1f,d1f,d1f,d1f}, {d1g,d1g,d1g,d1g}, {d1o,d1o,d1o,d1o} };
    mmR<4>(acc1, hA, 136, W9, lane);
    mmL<4>(acc1, hB, 136, A10L, w, lane);
    u16 hq1[4];
    cellfin(acc1, c1, hq1);
    __syncthreads();  // B3
#pragma unroll
    for (int q = 0; q < 4; ++q) hB[(rg * 4 + q) * 136 + uu] = hq1[q];
    __syncthreads();  // B4
    // ---- fc_out + feedback (waves 0-3) ----
    if (w < 4) {
      f32x4 accP = {fob, fob, fob, fob};
#pragma unroll
      for (int kt = 0; kt < 4; ++kt) {
        bfrag a = ldA(hB, 136, kt, lane);
        bfrag b = *(const bfrag*)(A11L + ((size_t)(kt * 4 + w) * 64 + lane) * 8);
        accP = __builtin_amdgcn_mfma_f32_16x16x32_bf16(a, b, accP, 0, 0, 0);
      }
      int oc = 16 * w + (lane & 15);
#pragma unroll
      for (int q = 0; q < 4; ++q) {
        int row = rg * 4 + q;
        float p = accP[q];
        out[((size_t)(b0r + row) * T_ + t) * 64 + oc] = p;
        xb[row * 72 + oc] = f2bfu(p);
      }
    }
    __syncthreads();  // B5: xb visible for next step
  }
}

// ---------------- launch ----------------
extern "C" void kernel_launch(void* const* d_in, const int* in_sizes, int n_in,
                              void* d_out, int out_size, void* d_ws, size_t ws_size,
                              hipStream_t stream) {
  const float* x     = (const float*)d_in[0];
  const float* e0wih = (const float*)d_in[1];
  const float* e0whh = (const float*)d_in[2];
  const float* e0b   = (const float*)d_in[3];
  const float* e1wih = (const float*)d_in[4];
  const float* e1whh = (const float*)d_in[5];
  const float* e1b   = (const float*)d_in[6];
  const float* fczw  = (const float*)d_in[7];
  const float* fczb  = (const float*)d_in[8];
  const float* lng   = (const float*)d_in[9];
  const float* lnb   = (const float*)d_in[10];
  const float* fciw  = (const float*)d_in[11];
  const float* fcib  = (const float*)d_in[12];
  const float* d0wih = (const float*)d_in[13];
  const float* d0whh = (const float*)d_in[14];
  const float* d0b   = (const float*)d_in[15];
  const float* d1wih = (const float*)d_in[16];
  const float* d1whh = (const float*)d_in[17];
  const float* d1b   = (const float*)d_in[18];
  const float* fcow  = (const float*)d_in[19];
  const float* fcob  = (const float*)d_in[20];
  char* ws = (char*)d_ws;
  float* out = (float*)d_out;

  pack_kernel<<<PACK_GRID, 256, 0, stream>>>(e0wih, e0whh, e1wih, e1whh,
                                             d0wih, d0whh, d1wih, d1whh,
                                             fczw, fciw, fcow, ws);
  enc01_kernel<<<256, 512, 0, stream>>>(x, e0b, ws, out);
  enc2_kernel<<<128, 512, 0, stream>>>(e1b, fczb, lng, lnb, fcib, ws, out);
  dec_kernel<<<128, 512, 0, stream>>>(d0b, d1b, fcob, ws, out);
}